// Round 1
// baseline (298.876 us; speedup 1.0000x reference)
//
#include <hip/hip_runtime.h>

typedef short v8s __attribute__((ext_vector_type(8)));
typedef float v4f __attribute__((ext_vector_type(4)));

#define BATCH 16
#define NBATCH 128           // 2048 / 16
#define BH 16384             // B*H
#define TBH 33554432         // T*B*H

__device__ __forceinline__ ushort f2bf(float f) {
  // round-to-nearest-even fp32 -> bf16 (inputs finite, no NaN handling needed)
  uint u = __float_as_uint(f);
  u += 0x7FFF + ((u >> 16) & 1);
  return (ushort)(u >> 16);
}

// ---------------- Phase 1: xW[m,h] = sum_i x[m,i] * W[h,i], bf16 MFMA ----------------
// A = x [131072, 256] fp32, W = W_ih [256, 256] fp32 (B^T layout), C = bf16 [131072, 256]
__global__ __launch_bounds__(512) void indrnn_gemm(
    const float* __restrict__ A,
    const float* __restrict__ W,
    ushort* __restrict__ C)
{
  // BM=128, BN=256 (full H), BK=64; pad LDS rows 64->72 shorts to break bank conflicts
  __shared__ ushort As[128 * 72];
  __shared__ ushort Bs[256 * 72];

  const int tid  = threadIdx.x;
  const int lane = tid & 63;
  const int wid  = tid >> 6;    // 0..7
  const int wm   = wid >> 2;    // 0..1  (M dim, 64 rows each)
  const int wn   = wid & 3;     // 0..3  (N dim, 64 cols each)
  const int m0   = blockIdx.x * 128;

  const int l15 = lane & 15;
  const int lhi = lane >> 4;    // 0..3

  v4f acc[4][4] = {};

  for (int kc = 0; kc < 4; ++kc) {
    // stage A tile: 128 rows x 64 k (fp32 -> bf16), 2048 float4s over 512 threads
    #pragma unroll
    for (int j = 0; j < 4; ++j) {
      int f    = j * 512 + tid;
      int row  = f >> 4;
      int colf = f & 15;
      const float4 a4 = *(const float4*)(A + ((size_t)(m0 + row) << 8) + kc * 64 + colf * 4);
      ushort4 b4 = make_ushort4(f2bf(a4.x), f2bf(a4.y), f2bf(a4.z), f2bf(a4.w));
      *(ushort4*)(As + row * 72 + colf * 4) = b4;
    }
    // stage B tile (W): 256 rows x 64 k
    #pragma unroll
    for (int j = 0; j < 8; ++j) {
      int f    = j * 512 + tid;
      int row  = f >> 4;
      int colf = f & 15;
      const float4 a4 = *(const float4*)(W + ((size_t)row << 8) + kc * 64 + colf * 4);
      ushort4 b4 = make_ushort4(f2bf(a4.x), f2bf(a4.y), f2bf(a4.z), f2bf(a4.w));
      *(ushort4*)(Bs + row * 72 + colf * 4) = b4;
    }
    __syncthreads();

    #pragma unroll
    for (int kk = 0; kk < 2; ++kk) {
      const int koff = kk * 32 + lhi * 8;
      v8s af[4], bf[4];
      #pragma unroll
      for (int mt = 0; mt < 4; ++mt)
        af[mt] = *(const v8s*)(As + (wm * 64 + mt * 16 + l15) * 72 + koff);
      #pragma unroll
      for (int nt = 0; nt < 4; ++nt)
        bf[nt] = *(const v8s*)(Bs + (wn * 64 + nt * 16 + l15) * 72 + koff);
      #pragma unroll
      for (int mt = 0; mt < 4; ++mt)
        #pragma unroll
        for (int nt = 0; nt < 4; ++nt)
          acc[mt][nt] = __builtin_amdgcn_mfma_f32_16x16x32_bf16(af[mt], bf[nt], acc[mt][nt], 0, 0, 0);
    }
    __syncthreads();
  }

  // epilogue: C/D layout col=lane&15, row=(lane>>4)*4+reg
  #pragma unroll
  for (int mt = 0; mt < 4; ++mt) {
    #pragma unroll
    for (int nt = 0; nt < 4; ++nt) {
      #pragma unroll
      for (int r = 0; r < 4; ++r) {
        int row = m0 + wm * 64 + mt * 16 + lhi * 4 + r;
        int col = wn * 64 + nt * 16 + l15;
        C[((size_t)row << 8) + col] = f2bf(acc[mt][nt][r]);
      }
    }
  }
}

// ---------------- Phase 2: sequential scan, 1 thread per (b,h) channel ----------------
// h_t = relu(xw_t + w * h_{t-1}); out[t*BH + ch] = h_t; out[TBH + ch] = h_last
__global__ __launch_bounds__(64) void indrnn_scan(
    const ushort* __restrict__ xw,
    const float* __restrict__ h0,
    const float* __restrict__ w_hh,
    float* __restrict__ out)
{
  const int ch = blockIdx.x * 64 + threadIdx.x;   // 256 blocks x 64 = 16384 channels
  const float w = w_hh[ch & 255];
  float h = h0[ch];
  const ushort* px = xw + ch;
  float* po = out + ch;

  uint b0[BATCH], b1[BATCH], b2[BATCH], b3[BATCH];

  auto ld = [&](uint (&buf)[BATCH], int kb) {
    const ushort* p = px + (size_t)kb * BATCH * BH;
    #pragma unroll
    for (int j = 0; j < BATCH; ++j) buf[j] = p[(size_t)j * BH];
  };
  auto cp = [&](uint (&buf)[BATCH], int kb) {
    float* o = po + (size_t)kb * BATCH * BH;
    #pragma unroll
    for (int j = 0; j < BATCH; ++j) {
      float xv = __uint_as_float(buf[j] << 16);
      h = fmaxf(fmaf(h, w, xv), 0.0f);
      o[(size_t)j * BH] = h;
    }
  };

  ld(b0, 0); ld(b1, 1); ld(b2, 2); ld(b3, 3);
  for (int kb = 0; kb < NBATCH; kb += 4) {
    cp(b0, kb);     if (kb + 4 < NBATCH) ld(b0, kb + 4);
    cp(b1, kb + 1); if (kb + 5 < NBATCH) ld(b1, kb + 5);
    cp(b2, kb + 2); if (kb + 6 < NBATCH) ld(b2, kb + 6);
    cp(b3, kb + 3); if (kb + 7 < NBATCH) ld(b3, kb + 7);
  }
  out[(size_t)TBH + ch] = h;
}

extern "C" void kernel_launch(void* const* d_in, const int* in_sizes, int n_in,
                              void* d_out, int out_size, void* d_ws, size_t ws_size,
                              hipStream_t stream) {
  const float* x    = (const float*)d_in[0];   // [2048, 64, 256]
  const float* h0   = (const float*)d_in[1];   // [1, 64, 256]
  const float* W_ih = (const float*)d_in[2];   // [256, 256]
  const float* w_hh = (const float*)d_in[3];   // [256]
  float* out = (float*)d_out;                  // [T,B,H] ++ [1,B,H]
  ushort* xw = (ushort*)d_ws;                  // bf16 intermediate, 64 MB

  indrnn_gemm<<<dim3(1024), dim3(512), 0, stream>>>(x, W_ih, xw);
  indrnn_scan<<<dim3(256), dim3(64), 0, stream>>>(xw, h0, w_hh, out);
}